// Round 7
// baseline (680.376 us; speedup 1.0000x reference)
//
#include <hip/hip_runtime.h>
#include <stdint.h>

// ---- problem constants ----
constexpr int Hh = 512, Ww = 512;
constexpr int HW = Hh * Ww;
constexpr int C  = 32;
constexpr int B  = 2;
constexpr int NL = 50000;
constexpr int NR = 20000;
constexpr float EPS = 1e-5f;
constexpr float SCALE = 0.25f;        // 1/sqrt(16)

constexpr int GBL = (NL + NR + 255) / 256;   // pillar-parallel blocks
constexpr int LB  = (NL + 255) / 256;        // lidar blocks
constexpr int RB  = (NR + 255) / 256;        // radar blocks
constexpr int NTILE = 1024;                  // 32x32 tiles of 16x16 cells

// 3x3 INDEX_SHIFT order from reference
__device__ __constant__ int DX9[9] = {0,-1,1,0,-1,1,0,-1,1};
__device__ __constant__ int DY9[9] = {0,0,0,1,1,1,-1,-1,-1};

// ==================== 1) init grids + counters ====================
__global__ void init_k(int* __restrict__ li_grid, int* __restrict__ ra_grid,
                       uint8_t* __restrict__ rdy_grid, int* __restrict__ cnt) {
    int b = blockIdx.y;
    int cell = blockIdx.x * 256 + threadIdx.x;
    size_t g = (size_t)b * HW + cell;
    li_grid[g] = -1;
    ra_grid[g] = -1;
    rdy_grid[g] = 0xFF;
    if (b == 0 && cell < 4 * NTILE) cnt[cell] = 0;
}

// ==================== 2) count pillars per 16x16 tile ====================
__global__ void count_k(const int* __restrict__ li_c, const int* __restrict__ ra_c,
                        int* __restrict__ cnt) {
    int b = blockIdx.y;
    int i = blockIdx.x * 256 + threadIdx.x;
    if (i < NL) {
        int x = li_c[((size_t)b * NL + i) * 2 + 0];
        int y = li_c[((size_t)b * NL + i) * 2 + 1];
        int tile = ((x >> 4) << 5) | (y >> 4);
        atomicAdd(&cnt[(b * 2 + 0) * NTILE + tile], 1);
    } else if (i < NL + NR) {
        int j = i - NL;
        int x = ra_c[((size_t)b * NR + j) * 2 + 0];
        int y = ra_c[((size_t)b * NR + j) * 2 + 1];
        int tile = ((x >> 4) << 5) | (y >> 4);
        atomicAdd(&cnt[(b * 2 + 1) * NTILE + tile], 1);
    }
}

// ==================== 3) exclusive scan per (batch,modality) -> cursor ====================
__global__ void scan_k(const int* __restrict__ cnt, int* __restrict__ cursor) {
    int g = blockIdx.x;                       // 0..3 = b*2+mod
    const int* c = cnt + g * NTILE;
    int* cur = cursor + g * NTILE;
    __shared__ int s[NTILE];
    int t = threadIdx.x;
    int self = c[t];
    s[t] = self;
    __syncthreads();
    for (int off = 1; off < NTILE; off <<= 1) {
        int v = (t >= off) ? s[t - off] : 0;
        __syncthreads();
        s[t] += v;
        __syncthreads();
    }
    cur[t] = s[t] - self;                     // exclusive prefix
}

// ==================== 4) scatter (slot assign) + LN + 3 fused matvecs ====================
__global__ void scatter_proj_k(const int* __restrict__ li_c, const int* __restrict__ ra_c,
                               const int* __restrict__ ra_dy,
                               int* __restrict__ li_grid, int* __restrict__ ra_grid,
                               uint8_t* __restrict__ rdy_grid, int* __restrict__ cursor,
                               const float* __restrict__ li_f, const float* __restrict__ ra_f,
                               const float* __restrict__ ln_li_w, const float* __restrict__ ln_li_b,
                               const float* __restrict__ ln_ra_w, const float* __restrict__ ln_ra_b,
                               const float* __restrict__ a1iw, const float* __restrict__ a1ib,
                               const float* __restrict__ a2iw, const float* __restrict__ a2ib,
                               const float* __restrict__ q1w, const float* __restrict__ q1b,
                               const float* __restrict__ k1w, const float* __restrict__ k1b,
                               const float* __restrict__ v1w, const float* __restrict__ v1b,
                               const float* __restrict__ q2w, const float* __restrict__ q2b,
                               const float* __restrict__ k2w, const float* __restrict__ k2b,
                               const float* __restrict__ v2w, const float* __restrict__ v2b,
                               float* __restrict__ qp1, float* __restrict__ kp1, float* __restrict__ vp1,
                               float* __restrict__ qp2, float* __restrict__ kp2, float* __restrict__ vp2) {
    int bx = blockIdx.x, b = blockIdx.y, t = threadIdx.x;
    bool lidar = (bx < LB);
    int n = lidar ? NL : NR;
    int i = (lidar ? bx : bx - LB) * 256 + t;

    const float* feats = lidar ? li_f : ra_f;
    const float* lnw = lidar ? ln_li_w : ln_ra_w;
    const float* lnb = lidar ? ln_li_b : ln_ra_b;
    // lidar feeds q of branch1, k/v of branch2; radar feeds q of branch2, k/v of branch1
    const float* Asec[3] = { (lidar ? a1iw : a2iw) + 0 * C * C,
                             (lidar ? a2iw : a1iw) + 1 * C * C,
                             (lidar ? a2iw : a1iw) + 2 * C * C };
    const float* absec[3] = { (lidar ? a1ib : a2ib) + 0 * C,
                              (lidar ? a2ib : a1ib) + 1 * C,
                              (lidar ? a2ib : a1ib) + 2 * C };
    const float* Wsec[3] = { lidar ? q1w : q2w, lidar ? k2w : k1w, lidar ? v2w : v1w };
    const float* bsec[3] = { lidar ? q1b : q2b, lidar ? k2b : k1b, lidar ? v2b : v1b };
    float* outp[3] = { lidar ? qp1 : qp2, lidar ? kp2 : kp1, lidar ? vp2 : vp1 };

    __shared__ float sM[3][1024];
    __shared__ float sc[3][32];
    for (int p = t; p < 3072; p += 256) {
        int m = p >> 10, e = p & 1023, r = e >> 5, d = e & 31;
        float s = 0.f;
        #pragma unroll
        for (int c = 0; c < C; ++c) s += Asec[m][r * C + c] * Wsec[m][c * C + d];
        sM[m][e] = s;
    }
    if (t < 96) {
        int m = t >> 5, r = t & 31;
        float s = absec[m][r];
        #pragma unroll
        for (int c = 0; c < C; ++c) s += Asec[m][r * C + c] * bsec[m][c];
        sc[m][r] = s;
    }
    __syncthreads();
    if (i >= n) return;

    // slot assignment (spatially-ranked by 16x16 tile)
    int x = (lidar ? li_c : ra_c)[((size_t)b * n + i) * 2 + 0];
    int y = (lidar ? li_c : ra_c)[((size_t)b * n + i) * 2 + 1];
    int tile = ((x >> 4) << 5) | (y >> 4);
    int mod = lidar ? 0 : 1;
    int slot = atomicAdd(&cursor[(b * 2 + mod) * NTILE + tile], 1);
    size_t cellg = (size_t)b * HW + x * Ww + y;
    if (lidar) {
        li_grid[cellg] = slot;
    } else {
        ra_grid[cellg] = slot;
        if (ra_dy[(size_t)b * n + i] != 0) rdy_grid[cellg] = 0;
    }

    // LN
    float xv[C];
    const float4* f4 = (const float4*)(feats + ((size_t)b * n + i) * C);
    #pragma unroll
    for (int q = 0; q < 8; ++q) {
        float4 tv = f4[q];
        xv[4*q] = tv.x; xv[4*q+1] = tv.y; xv[4*q+2] = tv.z; xv[4*q+3] = tv.w;
    }
    float mu = 0.f;
    #pragma unroll
    for (int c = 0; c < C; ++c) mu += xv[c];
    mu *= (1.0f / C);
    float var = 0.f;
    #pragma unroll
    for (int c = 0; c < C; ++c) { float d = xv[c] - mu; var += d * d; }
    var *= (1.0f / C);
    float inv = 1.0f / sqrtf(var + EPS);
    #pragma unroll
    for (int c = 0; c < C; ++c) xv[c] = (xv[c] - mu) * inv * lnw[c] + lnb[c];

    // 3 matvecs -> maps at slot row
    #pragma unroll
    for (int m = 0; m < 3; ++m) {
        float4* o4 = (float4*)(outp[m] + ((size_t)b * n + slot) * C);
        #pragma unroll
        for (int rq = 0; rq < 8; ++rq) {
            float4 tv;
            float* tp = &tv.x;
            #pragma unroll
            for (int rr = 0; rr < 4; ++rr) {
                int r = rq * 4 + rr;
                float s = sc[m][r];
                #pragma unroll
                for (int d = 0; d < C; ++d) s += sM[m][r * C + d] * xv[d];
                tp[rr] = s;
            }
            o4[rq] = tv;
        }
    }
}

// ---- per-cell attention body (shared by both branches) ----
__device__ __forceinline__ void attn_cell(
        int x, int y,
        const float* __restrict__ qrow,
        const float* __restrict__ kmap, const float* __restrict__ vmap,
        const int* __restrict__ kv_grid,
        const float* sWo, const float* sbo, const float* spe,
        const float* skinv, const float* svinv,
        float* v) {
    int nidx[9];
    #pragma unroll
    for (int j = 0; j < 9; ++j) {
        int sx = x + DX9[j], sy = y + DY9[j];
        nidx[j] = (sx >= 0 && sx < Hh && sy >= 0 && sy < Ww) ? kv_grid[sx * Ww + sy] : -1;
    }
    float qp[C];
    const float4* qp4 = (const float4*)qrow;
    #pragma unroll
    for (int q = 0; q < 8; ++q) {
        float4 tv = qp4[q];
        qp[4*q] = tv.x; qp[4*q+1] = tv.y; qp[4*q+2] = tv.z; qp[4*q+3] = tv.w;
    }
    float sc0[9], sc1[9];
    #pragma unroll
    for (int j = 0; j < 9; ++j) {
        int idx = nidx[j];
        const float4* kp4 = (idx >= 0) ? (const float4*)(kmap + (size_t)idx * C)
                                       : (const float4*)skinv;
        float s0 = 0.f, s1 = 0.f;
        #pragma unroll
        for (int q = 0; q < 4; ++q) {
            float4 tv = kp4[q];
            s0 += qp[4*q] * tv.x + qp[4*q+1] * tv.y + qp[4*q+2] * tv.z + qp[4*q+3] * tv.w;
        }
        #pragma unroll
        for (int q = 4; q < 8; ++q) {
            float4 tv = kp4[q];
            s1 += qp[4*q] * tv.x + qp[4*q+1] * tv.y + qp[4*q+2] * tv.z + qp[4*q+3] * tv.w;
        }
        sc0[j] = s0 * SCALE; sc1[j] = s1 * SCALE;
    }
    float m0 = sc0[0], m1 = sc1[0];
    #pragma unroll
    for (int j = 1; j < 9; ++j) { m0 = fmaxf(m0, sc0[j]); m1 = fmaxf(m1, sc1[j]); }
    float sum0 = 0.f, sum1 = 0.f;
    #pragma unroll
    for (int j = 0; j < 9; ++j) {
        sc0[j] = expf(sc0[j] - m0); sum0 += sc0[j];
        sc1[j] = expf(sc1[j] - m1); sum1 += sc1[j];
    }
    float r0 = 1.0f / sum0, r1 = 1.0f / sum1;

    float o[C];
    #pragma unroll
    for (int c = 0; c < C; ++c) o[c] = 0.f;
    #pragma unroll
    for (int j = 0; j < 9; ++j) {
        float a0 = sc0[j] * r0, a1 = sc1[j] * r1;
        int idx = nidx[j];
        if (idx >= 0) {
            const float4* vp4 = (const float4*)(vmap + (size_t)idx * C);
            #pragma unroll
            for (int q = 0; q < 8; ++q) {
                float4 tv = vp4[q];
                float a = (q < 4) ? a0 : a1;
                o[4*q]   += a * (tv.x + spe[j * 32 + 4*q]);
                o[4*q+1] += a * (tv.y + spe[j * 32 + 4*q+1]);
                o[4*q+2] += a * (tv.z + spe[j * 32 + 4*q+2]);
                o[4*q+3] += a * (tv.w + spe[j * 32 + 4*q+3]);
            }
        } else {
            #pragma unroll
            for (int d = 0; d < 16; ++d) {
                o[d]      += a0 * svinv[d];
                o[16 + d] += a1 * svinv[16 + d];
            }
        }
    }
    #pragma unroll
    for (int r = 0; r < C; ++r) {
        float s = sbo[r];
        #pragma unroll
        for (int c = 0; c < C; ++c) s += sWo[r * C + c] * o[c];
        v[r] = s;
    }
}

// ==================== 5) thread-per-cell fused attn + densify (LDS-staged writes) ====================
__global__ void attn_canvas_k(const int* __restrict__ li_grid, const int* __restrict__ ra_grid,
                              const uint8_t* __restrict__ rdy_grid,
                              const float* __restrict__ qp1, const float* __restrict__ kp1,
                              const float* __restrict__ vp1, const float* __restrict__ qp2,
                              const float* __restrict__ kp2, const float* __restrict__ vp2,
                              const float* __restrict__ a1iw, const float* __restrict__ a1ib,
                              const float* __restrict__ a2iw, const float* __restrict__ a2ib,
                              const float* __restrict__ posw, const float* __restrict__ posb,
                              const float* __restrict__ a1ow, const float* __restrict__ a1ob,
                              const float* __restrict__ a2ow, const float* __restrict__ a2ob,
                              float* __restrict__ out_li, float* __restrict__ out_ra) {
    __shared__ alignas(16) float sWo1[1024], sWo2[1024];
    __shared__ alignas(16) float sbo1[32], sbo2[32];
    __shared__ alignas(16) float spe1[288], spe2[288];
    __shared__ alignas(16) float skinv1[32], svinv1[32], skinv2[32], svinv2[32];
    __shared__ alignas(16) float sOut[C * 256];       // 32 KB staging
    int t = threadIdx.x;
    for (int p = t; p < 1024; p += 256) { sWo1[p] = a1ow[p]; sWo2[p] = a2ow[p]; }
    if (t < 32) {
        sbo1[t] = a1ob[t]; sbo2[t] = a2ob[t];
        skinv1[t] = a1ib[32 + t]; svinv1[t] = a1ib[64 + t];
        skinv2[t] = a2ib[32 + t]; svinv2[t] = a2ib[64 + t];
    }
    for (int p = t; p < 576; p += 256) {              // projected pos-enc: A{1,2}v @ pe9[j]
        int br = p / 288; int e = p % 288; int j = e >> 5, r = e & 31;
        const float* Av = (br == 0 ? a1iw : a2iw) + 2 * C * C;
        float sx = (float)DX9[j], sy = (float)DY9[j];
        float s = 0.f;
        #pragma unroll
        for (int c = 0; c < C; ++c) {
            float pe = posw[c * 2 + 0] * sx + posw[c * 2 + 1] * sy + posb[c];
            s += Av[r * C + c] * pe;
        }
        (br == 0 ? spe1 : spe2)[e] = s;
    }
    __syncthreads();

    int b = blockIdx.y;
    int cell0 = blockIdx.x * 256;
    int cell = cell0 + t;
    int x = cell >> 9, y = cell & 511;
    size_t gidx = (size_t)b * HW + cell;

    int li = li_grid[gidx];
    int ra = ra_grid[gidx];
    const uint8_t* rdy = rdy_grid + (size_t)b * HW;

    float v[C];
    // ---- branch 1: lidar query at this cell (dy-gated) ----
    bool do1 = false;
    if (li >= 0) {
        #pragma unroll
        for (int dx = -2; dx <= 2 && !do1; ++dx) {
            int cx = x + dx;
            cx = (cx < 0) ? cx + 513 : (cx >= 513 ? cx - 513 : cx);
            if (cx == 512) continue;
            #pragma unroll
            for (int dyy = -2; dyy <= 2; ++dyy) {
                int cy = y + dyy;
                cy = (cy < 0) ? cy + 513 : (cy >= 513 ? cy - 513 : cy);
                if (cy == 512) continue;
                if (rdy[cx * Ww + cy] == 0) { do1 = true; break; }
            }
        }
    }
    if (do1) {
        attn_cell(x, y, qp1 + ((size_t)b * NL + li) * C,
                  kp1 + (size_t)b * NR * C, vp1 + (size_t)b * NR * C,
                  ra_grid + (size_t)b * HW, sWo1, sbo1, spe1, skinv1, svinv1, v);
    } else {
        #pragma unroll
        for (int c = 0; c < C; ++c) v[c] = 0.f;
    }
    // stage + coalesced float4 canvas write
    #pragma unroll
    for (int c = 0; c < C; ++c) sOut[c * 256 + t] = v[c];
    __syncthreads();
    {
        size_t base = (size_t)b * C * HW + cell0;
        #pragma unroll
        for (int s8 = 0; s8 < 8; ++s8) {
            int p = s8 * 256 + t;
            int c = p >> 6, g = p & 63;
            float4 val = *(const float4*)&sOut[c * 256 + 4 * g];
            *(float4*)&out_li[base + (size_t)c * HW + 4 * g] = val;
        }
    }
    __syncthreads();

    // ---- branch 2: radar query at this cell ----
    if (ra >= 0) {
        attn_cell(x, y, qp2 + ((size_t)b * NR + ra) * C,
                  kp2 + (size_t)b * NL * C, vp2 + (size_t)b * NL * C,
                  li_grid + (size_t)b * HW, sWo2, sbo2, spe2, skinv2, svinv2, v);
    } else {
        #pragma unroll
        for (int c = 0; c < C; ++c) v[c] = 0.f;
    }
    #pragma unroll
    for (int c = 0; c < C; ++c) sOut[c * 256 + t] = v[c];
    __syncthreads();
    {
        size_t base = (size_t)b * C * HW + cell0;
        #pragma unroll
        for (int s8 = 0; s8 < 8; ++s8) {
            int p = s8 * 256 + t;
            int c = p >> 6, g = p & 63;
            float4 val = *(const float4*)&sOut[c * 256 + 4 * g];
            *(float4*)&out_ra[base + (size_t)c * HW + 4 * g] = val;
        }
    }
}

extern "C" void kernel_launch(void* const* d_in, const int* in_sizes, int n_in,
                              void* d_out, int out_size, void* d_ws, size_t ws_size,
                              hipStream_t stream) {
    const float*   li_f  = (const float*)d_in[0];
    const int*     li_c  = (const int*)d_in[1];
    const float*   ra_f  = (const float*)d_in[2];
    const int*     ra_c  = (const int*)d_in[3];
    const int*     ra_dy = (const int*)d_in[4];   // jnp bool staged as int32
    const float* ln_li_w = (const float*)d_in[5];
    const float* ln_li_b = (const float*)d_in[6];
    const float* ln_ra_w = (const float*)d_in[7];
    const float* ln_ra_b = (const float*)d_in[8];
    const float* q1w = (const float*)d_in[9],  *q1b = (const float*)d_in[10];
    const float* k1w = (const float*)d_in[11], *k1b = (const float*)d_in[12];
    const float* v1w = (const float*)d_in[13], *v1b = (const float*)d_in[14];
    const float* q2w = (const float*)d_in[15], *q2b = (const float*)d_in[16];
    const float* k2w = (const float*)d_in[17], *k2b = (const float*)d_in[18];
    const float* v2w = (const float*)d_in[19], *v2b = (const float*)d_in[20];
    const float* posw = (const float*)d_in[21], *posb = (const float*)d_in[22];
    const float* a1iw = (const float*)d_in[23], *a1ib = (const float*)d_in[24];
    const float* a1ow = (const float*)d_in[25], *a1ob = (const float*)d_in[26];
    const float* a2iw = (const float*)d_in[27], *a2ib = (const float*)d_in[28];
    const float* a2ow = (const float*)d_in[29], *a2ob = (const float*)d_in[30];

    // ---- workspace carve-up (256B aligned) ----
    char* ws = (char*)d_ws;
    size_t off = 0;
    auto carve = [&](size_t bytes) { void* p = ws + off; off += (bytes + 255) & ~(size_t)255; return p; };
    int*     li_grid  = (int*)carve((size_t)B * HW * 4);
    int*     ra_grid  = (int*)carve((size_t)B * HW * 4);
    uint8_t* rdy_grid = (uint8_t*)carve((size_t)B * HW);
    int*     cnt      = (int*)carve((size_t)4 * NTILE * 4);
    int*     cursor   = (int*)carve((size_t)4 * NTILE * 4);
    float*   qp1 = (float*)carve((size_t)B * NL * C * 4);
    float*   kp1 = (float*)carve((size_t)B * NR * C * 4);
    float*   vp1 = (float*)carve((size_t)B * NR * C * 4);
    float*   qp2 = (float*)carve((size_t)B * NR * C * 4);
    float*   kp2 = (float*)carve((size_t)B * NL * C * 4);
    float*   vp2 = (float*)carve((size_t)B * NL * C * 4);
    (void)ws_size; (void)n_in; (void)in_sizes; (void)out_size;

    float* out_li = (float*)d_out;
    float* out_ra = out_li + (size_t)B * C * HW;

    // 1) init grids/rdy/counters
    init_k<<<dim3(HW / 256, B), dim3(256), 0, stream>>>(li_grid, ra_grid, rdy_grid, cnt);
    // 2) tile histogram
    count_k<<<dim3(GBL, B), dim3(256), 0, stream>>>(li_c, ra_c, cnt);
    // 3) exclusive scan -> cursor
    scan_k<<<dim3(4), dim3(NTILE), 0, stream>>>(cnt, cursor);
    // 4) slot scatter + LN + projections (maps in spatially-ranked slot order)
    scatter_proj_k<<<dim3(LB + RB, B), dim3(256), 0, stream>>>(
        li_c, ra_c, ra_dy, li_grid, ra_grid, rdy_grid, cursor,
        li_f, ra_f, ln_li_w, ln_li_b, ln_ra_w, ln_ra_b,
        a1iw, a1ib, a2iw, a2ib,
        q1w, q1b, k1w, k1b, v1w, v1b, q2w, q2b, k2w, k2b, v2w, v2b,
        qp1, kp1, vp1, qp2, kp2, vp2);
    // 5) fused attention + densification
    attn_canvas_k<<<dim3(HW / 256, B), dim3(256), 0, stream>>>(
        li_grid, ra_grid, rdy_grid, qp1, kp1, vp1, qp2, kp2, vp2,
        a1iw, a1ib, a2iw, a2ib, posw, posb, a1ow, a1ob, a2ow, a2ob,
        out_li, out_ra);
}

// Round 9
// 405.307 us; speedup vs baseline: 1.6787x; 1.6787x over previous
//
#include <hip/hip_runtime.h>
#include <stdint.h>

// ---- problem constants ----
constexpr int Hh = 512, Ww = 512;
constexpr int HW = Hh * Ww;
constexpr int C  = 32;
constexpr int B  = 2;
constexpr int NL = 50000;
constexpr int NR = 20000;
constexpr float EPS = 1e-5f;
constexpr float SCALE = 0.25f;        // 1/sqrt(16)

constexpr int GBL = (NL + NR + 255) / 256;   // pillar-parallel blocks
constexpr int LB  = (NL + 255) / 256;        // lidar blocks (196)
constexpr int RB  = (NR + 255) / 256;        // radar blocks (79)
constexpr int NTILE = 1024;                  // 32x32 tiles of 16x16 cells

// 3x3 INDEX_SHIFT order from reference
__device__ __constant__ int DX9[9] = {0,-1,1,0,-1,1,0,-1,1};
__device__ __constant__ int DY9[9] = {0,0,0,1,1,1,-1,-1,-1};

// bijective XCD swizzle (8 XCDs): consecutive logical work chunks land on one XCD's L2
__device__ __forceinline__ int xcd_swz(int bid, int nb) {
    int q = nb >> 3, r = nb & 7;
    int xcd = bid & 7, idx = bid >> 3;
    return (xcd < r) ? xcd * (q + 1) + idx : r * (q + 1) + (xcd - r) * q + idx;
}

// ==================== 1) count pillars per 16x16 tile ====================
__global__ void count_k(const int* __restrict__ li_c, const int* __restrict__ ra_c,
                        int* __restrict__ cnt) {
    int b = blockIdx.y;
    int i = blockIdx.x * 256 + threadIdx.x;
    if (i < NL) {
        int x = li_c[((size_t)b * NL + i) * 2 + 0];
        int y = li_c[((size_t)b * NL + i) * 2 + 1];
        int tile = ((x >> 4) << 5) | (y >> 4);
        atomicAdd(&cnt[(b * 2 + 0) * NTILE + tile], 1);
    } else if (i < NL + NR) {
        int j = i - NL;
        int x = ra_c[((size_t)b * NR + j) * 2 + 0];
        int y = ra_c[((size_t)b * NR + j) * 2 + 1];
        int tile = ((x >> 4) << 5) | (y >> 4);
        atomicAdd(&cnt[(b * 2 + 1) * NTILE + tile], 1);
    }
}

// ==================== 2) exclusive scan per (batch,modality) -> cursor ====================
__global__ void scan_k(const int* __restrict__ cnt, int* __restrict__ cursor) {
    int g = blockIdx.x;                       // 0..3 = b*2+mod
    const int* c = cnt + g * NTILE;
    int* cur = cursor + g * NTILE;
    __shared__ int s[NTILE];
    int t = threadIdx.x;
    int self = c[t];
    s[t] = self;
    __syncthreads();
    for (int off = 1; off < NTILE; off <<= 1) {
        int v = (t >= off) ? s[t - off] : 0;
        __syncthreads();
        s[t] += v;
        __syncthreads();
    }
    cur[t] = s[t] - self;                     // exclusive prefix
}

// ==================== 3) slot scatter + LN + 3 fused matvecs ====================
__global__ void scatter_proj_k(const int* __restrict__ li_c, const int* __restrict__ ra_c,
                               const int* __restrict__ ra_dy,
                               int* __restrict__ li_grid, int* __restrict__ ra_grid,
                               uint8_t* __restrict__ rdy_grid, int* __restrict__ cursor,
                               int* __restrict__ lixy, int* __restrict__ raxy,
                               const float* __restrict__ li_f, const float* __restrict__ ra_f,
                               const float* __restrict__ ln_li_w, const float* __restrict__ ln_li_b,
                               const float* __restrict__ ln_ra_w, const float* __restrict__ ln_ra_b,
                               const float* __restrict__ a1iw, const float* __restrict__ a1ib,
                               const float* __restrict__ a2iw, const float* __restrict__ a2ib,
                               const float* __restrict__ q1w, const float* __restrict__ q1b,
                               const float* __restrict__ k1w, const float* __restrict__ k1b,
                               const float* __restrict__ v1w, const float* __restrict__ v1b,
                               const float* __restrict__ q2w, const float* __restrict__ q2b,
                               const float* __restrict__ k2w, const float* __restrict__ k2b,
                               const float* __restrict__ v2w, const float* __restrict__ v2b,
                               float* __restrict__ qp1, float* __restrict__ kp1, float* __restrict__ vp1,
                               float* __restrict__ qp2, float* __restrict__ kp2, float* __restrict__ vp2) {
    int bx = blockIdx.x, b = blockIdx.y, t = threadIdx.x;
    bool lidar = (bx < LB);
    int n = lidar ? NL : NR;
    int i = (lidar ? bx : bx - LB) * 256 + t;

    const float* feats = lidar ? li_f : ra_f;
    const float* lnw = lidar ? ln_li_w : ln_ra_w;
    const float* lnb = lidar ? ln_li_b : ln_ra_b;
    // lidar feeds q of branch1, k/v of branch2; radar feeds q of branch2, k/v of branch1
    const float* Asec[3] = { (lidar ? a1iw : a2iw) + 0 * C * C,
                             (lidar ? a2iw : a1iw) + 1 * C * C,
                             (lidar ? a2iw : a1iw) + 2 * C * C };
    const float* absec[3] = { (lidar ? a1ib : a2ib) + 0 * C,
                              (lidar ? a2ib : a1ib) + 1 * C,
                              (lidar ? a2ib : a1ib) + 2 * C };
    const float* Wsec[3] = { lidar ? q1w : q2w, lidar ? k2w : k1w, lidar ? v2w : v1w };
    const float* bsec[3] = { lidar ? q1b : q2b, lidar ? k2b : k1b, lidar ? v2b : v1b };
    float* outp[3] = { lidar ? qp1 : qp2, lidar ? kp2 : kp1, lidar ? vp2 : vp1 };

    __shared__ float sM[3][1024];
    __shared__ float sc[3][32];
    for (int p = t; p < 3072; p += 256) {
        int m = p >> 10, e = p & 1023, r = e >> 5, d = e & 31;
        float s = 0.f;
        #pragma unroll
        for (int c = 0; c < C; ++c) s += Asec[m][r * C + c] * Wsec[m][c * C + d];
        sM[m][e] = s;
    }
    if (t < 96) {
        int m = t >> 5, r = t & 31;
        float s = absec[m][r];
        #pragma unroll
        for (int c = 0; c < C; ++c) s += Asec[m][r * C + c] * bsec[m][c];
        sc[m][r] = s;
    }
    __syncthreads();
    if (i >= n) return;

    // slot assignment (spatially-ranked by 16x16 tile)
    int x = (lidar ? li_c : ra_c)[((size_t)b * n + i) * 2 + 0];
    int y = (lidar ? li_c : ra_c)[((size_t)b * n + i) * 2 + 1];
    int tile = ((x >> 4) << 5) | (y >> 4);
    int mod = lidar ? 0 : 1;
    int slot = atomicAdd(&cursor[(b * 2 + mod) * NTILE + tile], 1);
    size_t cellg = (size_t)b * HW + x * Ww + y;
    if (lidar) {
        li_grid[cellg] = slot;
        lixy[(size_t)b * NL + slot] = (x << 16) | y;
    } else {
        ra_grid[cellg] = slot;
        raxy[(size_t)b * NR + slot] = (x << 16) | y;
        if (ra_dy[(size_t)b * n + i] != 0) rdy_grid[cellg] = 0;
    }

    // LN
    float xv[C];
    const float4* f4 = (const float4*)(feats + ((size_t)b * n + i) * C);
    #pragma unroll
    for (int q = 0; q < 8; ++q) {
        float4 tv = f4[q];
        xv[4*q] = tv.x; xv[4*q+1] = tv.y; xv[4*q+2] = tv.z; xv[4*q+3] = tv.w;
    }
    float mu = 0.f;
    #pragma unroll
    for (int c = 0; c < C; ++c) mu += xv[c];
    mu *= (1.0f / C);
    float var = 0.f;
    #pragma unroll
    for (int c = 0; c < C; ++c) { float d = xv[c] - mu; var += d * d; }
    var *= (1.0f / C);
    float inv = 1.0f / sqrtf(var + EPS);
    #pragma unroll
    for (int c = 0; c < C; ++c) xv[c] = (xv[c] - mu) * inv * lnw[c] + lnb[c];

    // 3 matvecs -> maps at slot row
    #pragma unroll
    for (int m = 0; m < 3; ++m) {
        float4* o4 = (float4*)(outp[m] + ((size_t)b * n + slot) * C);
        #pragma unroll
        for (int rq = 0; rq < 8; ++rq) {
            float4 tv;
            float* tp = &tv.x;
            #pragma unroll
            for (int rr = 0; rr < 4; ++rr) {
                int r = rq * 4 + rr;
                float s = sc[m][r];
                #pragma unroll
                for (int d = 0; d < C; ++d) s += sM[m][r * C + d] * xv[d];
                tp[rr] = s;
            }
            o4[rq] = tv;
        }
    }
}

// ---- per-query attention body ----
__device__ __forceinline__ void attn_cell(
        int x, int y,
        const float* __restrict__ qrow,
        const float* __restrict__ kmap, const float* __restrict__ vmap,
        const int* __restrict__ kv_grid,
        const float* sWo, const float* sbo, const float* spe,
        const float* skinv, const float* svinv,
        float* v) {
    int nidx[9];
    #pragma unroll
    for (int j = 0; j < 9; ++j) {
        int sx = x + DX9[j], sy = y + DY9[j];
        nidx[j] = (sx >= 0 && sx < Hh && sy >= 0 && sy < Ww) ? kv_grid[sx * Ww + sy] : -1;
    }
    float qp[C];
    const float4* qp4 = (const float4*)qrow;
    #pragma unroll
    for (int q = 0; q < 8; ++q) {
        float4 tv = qp4[q];
        qp[4*q] = tv.x; qp[4*q+1] = tv.y; qp[4*q+2] = tv.z; qp[4*q+3] = tv.w;
    }
    float sc0[9], sc1[9];
    #pragma unroll
    for (int j = 0; j < 9; ++j) {
        int idx = nidx[j];
        const float4* kp4 = (idx >= 0) ? (const float4*)(kmap + (size_t)idx * C)
                                       : (const float4*)skinv;
        float s0 = 0.f, s1 = 0.f;
        #pragma unroll
        for (int q = 0; q < 4; ++q) {
            float4 tv = kp4[q];
            s0 += qp[4*q] * tv.x + qp[4*q+1] * tv.y + qp[4*q+2] * tv.z + qp[4*q+3] * tv.w;
        }
        #pragma unroll
        for (int q = 4; q < 8; ++q) {
            float4 tv = kp4[q];
            s1 += qp[4*q] * tv.x + qp[4*q+1] * tv.y + qp[4*q+2] * tv.z + qp[4*q+3] * tv.w;
        }
        sc0[j] = s0 * SCALE; sc1[j] = s1 * SCALE;
    }
    float m0 = sc0[0], m1 = sc1[0];
    #pragma unroll
    for (int j = 1; j < 9; ++j) { m0 = fmaxf(m0, sc0[j]); m1 = fmaxf(m1, sc1[j]); }
    float sum0 = 0.f, sum1 = 0.f;
    #pragma unroll
    for (int j = 0; j < 9; ++j) {
        sc0[j] = expf(sc0[j] - m0); sum0 += sc0[j];
        sc1[j] = expf(sc1[j] - m1); sum1 += sc1[j];
    }
    float r0 = 1.0f / sum0, r1 = 1.0f / sum1;

    float o[C];
    #pragma unroll
    for (int c = 0; c < C; ++c) o[c] = 0.f;
    #pragma unroll
    for (int j = 0; j < 9; ++j) {
        float a0 = sc0[j] * r0, a1 = sc1[j] * r1;
        int idx = nidx[j];
        if (idx >= 0) {
            const float4* vp4 = (const float4*)(vmap + (size_t)idx * C);
            #pragma unroll
            for (int q = 0; q < 8; ++q) {
                float4 tv = vp4[q];
                float a = (q < 4) ? a0 : a1;
                o[4*q]   += a * (tv.x + spe[j * 32 + 4*q]);
                o[4*q+1] += a * (tv.y + spe[j * 32 + 4*q+1]);
                o[4*q+2] += a * (tv.z + spe[j * 32 + 4*q+2]);
                o[4*q+3] += a * (tv.w + spe[j * 32 + 4*q+3]);
            }
        } else {
            #pragma unroll
            for (int d = 0; d < 16; ++d) {
                o[d]      += a0 * svinv[d];
                o[16 + d] += a1 * svinv[16 + d];
            }
        }
    }
    #pragma unroll
    for (int r = 0; r < C; ++r) {
        float s = sbo[r];
        #pragma unroll
        for (int c = 0; c < C; ++c) s += sWo[r * C + c] * o[c];
        v[r] = s;
    }
}

// ==================== 4) slot-ordered pillar-parallel attention ====================
__global__ void attn_slot_k(const int* __restrict__ li_grid, const int* __restrict__ ra_grid,
                            const uint8_t* __restrict__ rdy_grid,
                            const int* __restrict__ lixy, const int* __restrict__ raxy,
                            const float* __restrict__ qp1, const float* __restrict__ kp1,
                            const float* __restrict__ vp1, const float* __restrict__ qp2,
                            const float* __restrict__ kp2, const float* __restrict__ vp2,
                            const float* __restrict__ a1iw, const float* __restrict__ a1ib,
                            const float* __restrict__ a2iw, const float* __restrict__ a2ib,
                            const float* __restrict__ posw, const float* __restrict__ posb,
                            const float* __restrict__ a1ow, const float* __restrict__ a1ob,
                            const float* __restrict__ a2ow, const float* __restrict__ a2ob,
                            float* __restrict__ feat1, float* __restrict__ feat2) {
    int wg = xcd_swz(blockIdx.x, LB + RB);
    bool br1 = (wg < LB);
    int n = br1 ? NL : NR;
    int i = (br1 ? wg : wg - LB) * 256 + threadIdx.x;
    int b = blockIdx.y;
    int t = threadIdx.x;

    const float* Wo = br1 ? a1ow : a2ow;
    const float* bo = br1 ? a1ob : a2ob;
    const float* Aib = br1 ? a1ib : a2ib;
    const float* Av  = (br1 ? a1iw : a2iw) + 2 * C * C;
    __shared__ alignas(16) float sWo[1024];
    __shared__ alignas(16) float sbo[32], skinv[32], svinv[32];
    __shared__ alignas(16) float spe[288];
    for (int p = t; p < 1024; p += 256) sWo[p] = Wo[p];
    if (t < 32) {
        sbo[t] = bo[t];
        skinv[t] = Aib[32 + t];
        svinv[t] = Aib[64 + t];
    }
    for (int e = t; e < 288; e += 256) {      // projected pos-enc (FIXED: strided, covers all 288)
        int j = e >> 5, r = e & 31;
        float sx = (float)DX9[j], sy = (float)DY9[j];
        float s = 0.f;
        #pragma unroll
        for (int c = 0; c < C; ++c) {
            float pe = posw[c * 2 + 0] * sx + posw[c * 2 + 1] * sy + posb[c];
            s += Av[r * C + c] * pe;
        }
        spe[e] = s;
    }
    __syncthreads();
    if (i >= n) return;

    int pc = (br1 ? lixy : raxy)[(size_t)b * n + i];
    int x = pc >> 16, y = pc & 0xFFFF;

    float v[C];
    if (br1) {
        // dy gate: 5x5 window with mod-513 wrap (reference semantics; coord 512 invalid)
        const uint8_t* rdy = rdy_grid + (size_t)b * HW;
        bool dy = false;
        #pragma unroll
        for (int dx = -2; dx <= 2 && !dy; ++dx) {
            int cx = x + dx;
            cx = (cx < 0) ? cx + 513 : (cx >= 513 ? cx - 513 : cx);
            if (cx == 512) continue;
            #pragma unroll
            for (int dyy = -2; dyy <= 2; ++dyy) {
                int cy = y + dyy;
                cy = (cy < 0) ? cy + 513 : (cy >= 513 ? cy - 513 : cy);
                if (cy == 512) continue;
                if (rdy[cx * Ww + cy] == 0) { dy = true; break; }
            }
        }
        if (dy) {
            attn_cell(x, y, qp1 + ((size_t)b * NL + i) * C,
                      kp1 + (size_t)b * NR * C, vp1 + (size_t)b * NR * C,
                      ra_grid + (size_t)b * HW, sWo, sbo, spe, skinv, svinv, v);
        } else {
            #pragma unroll
            for (int c = 0; c < C; ++c) v[c] = 0.f;
        }
        float4* o4 = (float4*)(feat1 + ((size_t)b * NL + i) * C);
        #pragma unroll
        for (int q = 0; q < 8; ++q) o4[q] = *(float4*)&v[4*q];
    } else {
        attn_cell(x, y, qp2 + ((size_t)b * NR + i) * C,
                  kp2 + (size_t)b * NL * C, vp2 + (size_t)b * NL * C,
                  li_grid + (size_t)b * HW, sWo, sbo, spe, skinv, svinv, v);
        float4* o4 = (float4*)(feat2 + ((size_t)b * NR + i) * C);
        #pragma unroll
        for (int q = 0; q < 8; ++q) o4[q] = *(float4*)&v[4*q];
    }
}

// ==================== 5) densify: thread per cell, coalesced canvas writes ====================
__global__ void canvas_k(const int* __restrict__ li_grid, const int* __restrict__ ra_grid,
                         const float* __restrict__ feat1, const float* __restrict__ feat2,
                         float* __restrict__ out_li, float* __restrict__ out_ra) {
    int b = blockIdx.y;
    int wg = xcd_swz(blockIdx.x, HW / 256);
    int cell = wg * 256 + threadIdx.x;
    size_t gidx = (size_t)b * HW + cell;
    size_t obase = (size_t)b * C * HW + cell;

    int li = li_grid[gidx];
    float v[C];
    if (li >= 0) {
        const float4* f = (const float4*)(feat1 + ((size_t)b * NL + li) * C);
        #pragma unroll
        for (int q = 0; q < 8; ++q) {
            float4 t = f[q];
            v[4*q] = t.x; v[4*q+1] = t.y; v[4*q+2] = t.z; v[4*q+3] = t.w;
        }
    } else {
        #pragma unroll
        for (int c = 0; c < C; ++c) v[c] = 0.f;
    }
    #pragma unroll
    for (int c = 0; c < C; ++c) out_li[obase + (size_t)c * HW] = v[c];

    int ra = ra_grid[gidx];
    if (ra >= 0) {
        const float4* f = (const float4*)(feat2 + ((size_t)b * NR + ra) * C);
        #pragma unroll
        for (int q = 0; q < 8; ++q) {
            float4 t = f[q];
            v[4*q] = t.x; v[4*q+1] = t.y; v[4*q+2] = t.z; v[4*q+3] = t.w;
        }
    } else {
        #pragma unroll
        for (int c = 0; c < C; ++c) v[c] = 0.f;
    }
    #pragma unroll
    for (int c = 0; c < C; ++c) out_ra[obase + (size_t)c * HW] = v[c];
}

extern "C" void kernel_launch(void* const* d_in, const int* in_sizes, int n_in,
                              void* d_out, int out_size, void* d_ws, size_t ws_size,
                              hipStream_t stream) {
    const float*   li_f  = (const float*)d_in[0];
    const int*     li_c  = (const int*)d_in[1];
    const float*   ra_f  = (const float*)d_in[2];
    const int*     ra_c  = (const int*)d_in[3];
    const int*     ra_dy = (const int*)d_in[4];   // jnp bool staged as int32
    const float* ln_li_w = (const float*)d_in[5];
    const float* ln_li_b = (const float*)d_in[6];
    const float* ln_ra_w = (const float*)d_in[7];
    const float* ln_ra_b = (const float*)d_in[8];
    const float* q1w = (const float*)d_in[9],  *q1b = (const float*)d_in[10];
    const float* k1w = (const float*)d_in[11], *k1b = (const float*)d_in[12];
    const float* v1w = (const float*)d_in[13], *v1b = (const float*)d_in[14];
    const float* q2w = (const float*)d_in[15], *q2b = (const float*)d_in[16];
    const float* k2w = (const float*)d_in[17], *k2b = (const float*)d_in[18];
    const float* v2w = (const float*)d_in[19], *v2b = (const float*)d_in[20];
    const float* posw = (const float*)d_in[21], *posb = (const float*)d_in[22];
    const float* a1iw = (const float*)d_in[23], *a1ib = (const float*)d_in[24];
    const float* a1ow = (const float*)d_in[25], *a1ob = (const float*)d_in[26];
    const float* a2iw = (const float*)d_in[27], *a2ib = (const float*)d_in[28];
    const float* a2ow = (const float*)d_in[29], *a2ob = (const float*)d_in[30];

    // ---- workspace carve-up (256B aligned); grids+rdy contiguous for one memset ----
    char* ws = (char*)d_ws;
    size_t off = 0;
    auto carve = [&](size_t bytes) { void* p = ws + off; off += (bytes + 255) & ~(size_t)255; return p; };
    int*     li_grid  = (int*)carve((size_t)B * HW * 4);
    int*     ra_grid  = (int*)carve((size_t)B * HW * 4);
    uint8_t* rdy_grid = (uint8_t*)carve((size_t)B * HW);
    size_t   init_bytes = off;                             // -> 0xFF
    int*     cnt      = (int*)carve((size_t)4 * NTILE * 4);
    int*     cursor   = (int*)carve((size_t)4 * NTILE * 4);
    int*     lixy     = (int*)carve((size_t)B * NL * 4);
    int*     raxy     = (int*)carve((size_t)B * NR * 4);
    float*   qp1 = (float*)carve((size_t)B * NL * C * 4);
    float*   kp1 = (float*)carve((size_t)B * NR * C * 4);
    float*   vp1 = (float*)carve((size_t)B * NR * C * 4);
    float*   qp2 = (float*)carve((size_t)B * NR * C * 4);
    float*   kp2 = (float*)carve((size_t)B * NL * C * 4);
    float*   vp2 = (float*)carve((size_t)B * NL * C * 4);
    float*   feat1 = (float*)carve((size_t)B * NL * C * 4);
    float*   feat2 = (float*)carve((size_t)B * NR * C * 4);
    (void)ws_size; (void)n_in; (void)in_sizes; (void)out_size;

    float* out_li = (float*)d_out;
    float* out_ra = out_li + (size_t)B * C * HW;

    // 1) grids -1 / rdy 0xFF ; 2) cnt = 0
    hipMemsetAsync(li_grid, 0xFF, init_bytes, stream);
    hipMemsetAsync(cnt, 0, (size_t)4 * NTILE * 4, stream);

    // 3) tile histogram
    count_k<<<dim3(GBL, B), dim3(256), 0, stream>>>(li_c, ra_c, cnt);
    // 4) exclusive scan -> cursor
    scan_k<<<dim3(4), dim3(NTILE), 0, stream>>>(cnt, cursor);
    // 5) slot scatter + LN + projections (maps in spatially-ranked slot order)
    scatter_proj_k<<<dim3(LB + RB, B), dim3(256), 0, stream>>>(
        li_c, ra_c, ra_dy, li_grid, ra_grid, rdy_grid, cursor, lixy, raxy,
        li_f, ra_f, ln_li_w, ln_li_b, ln_ra_w, ln_ra_b,
        a1iw, a1ib, a2iw, a2ib,
        q1w, q1b, k1w, k1b, v1w, v1b, q2w, q2b, k2w, k2b, v2w, v2b,
        qp1, kp1, vp1, qp2, kp2, vp2);
    // 6) slot-ordered dense attention (XCD-swizzled)
    attn_slot_k<<<dim3(LB + RB, B), dim3(256), 0, stream>>>(
        li_grid, ra_grid, rdy_grid, lixy, raxy,
        qp1, kp1, vp1, qp2, kp2, vp2,
        a1iw, a1ib, a2iw, a2ib, posw, posb, a1ow, a1ob, a2ow, a2ob,
        feat1, feat2);
    // 7) densify (XCD-swizzled, coalesced writes)
    canvas_k<<<dim3(HW / 256, B), dim3(256), 0, stream>>>(
        li_grid, ra_grid, feat1, feat2, out_li, out_ra);
}

// Round 10
// 348.320 us; speedup vs baseline: 1.9533x; 1.1636x over previous
//
#include <hip/hip_runtime.h>
#include <stdint.h>

// ---- problem constants ----
constexpr int Hh = 512, Ww = 512;
constexpr int HW = Hh * Ww;
constexpr int C  = 32;
constexpr int B  = 2;
constexpr int NL = 50000;
constexpr int NR = 20000;
constexpr float EPS = 1e-5f;
constexpr float SCALE = 0.25f;        // 1/sqrt(16)

constexpr int GBL = (NL + NR + 255) / 256;   // pillar-parallel blocks
constexpr int LB  = (NL + 255) / 256;        // lidar blocks (196) for proj
constexpr int RB  = (NR + 255) / 256;        // radar blocks (79)
constexpr int LB2 = (NL + 127) / 128;        // lidar blocks (391) for head-split attn
constexpr int RB2 = (NR + 127) / 128;        // radar blocks (157)
constexpr int NTILE = 1024;                  // 32x32 tiles of 16x16 cells

// 3x3 INDEX_SHIFT order from reference
__device__ __constant__ int DX9[9] = {0,-1,1,0,-1,1,0,-1,1};
__device__ __constant__ int DY9[9] = {0,0,0,1,1,1,-1,-1,-1};

// ==================== 1) count pillars per 16x16 tile ====================
__global__ void count_k(const int* __restrict__ li_c, const int* __restrict__ ra_c,
                        int* __restrict__ cnt) {
    int b = blockIdx.y;
    int i = blockIdx.x * 256 + threadIdx.x;
    if (i < NL) {
        int x = li_c[((size_t)b * NL + i) * 2 + 0];
        int y = li_c[((size_t)b * NL + i) * 2 + 1];
        int tile = ((x >> 4) << 5) | (y >> 4);
        atomicAdd(&cnt[(b * 2 + 0) * NTILE + tile], 1);
    } else if (i < NL + NR) {
        int j = i - NL;
        int x = ra_c[((size_t)b * NR + j) * 2 + 0];
        int y = ra_c[((size_t)b * NR + j) * 2 + 1];
        int tile = ((x >> 4) << 5) | (y >> 4);
        atomicAdd(&cnt[(b * 2 + 1) * NTILE + tile], 1);
    }
}

// ==================== 2) exclusive scan per (batch,modality) -> cursor ====================
__global__ void scan_k(const int* __restrict__ cnt, int* __restrict__ cursor) {
    int g = blockIdx.x;                       // 0..3 = b*2+mod
    const int* c = cnt + g * NTILE;
    int* cur = cursor + g * NTILE;
    __shared__ int s[NTILE];
    int t = threadIdx.x;
    int self = c[t];
    s[t] = self;
    __syncthreads();
    for (int off = 1; off < NTILE; off <<= 1) {
        int v = (t >= off) ? s[t - off] : 0;
        __syncthreads();
        s[t] += v;
        __syncthreads();
    }
    cur[t] = s[t] - self;                     // exclusive prefix
}

// ==================== 3) slot scatter + LN + 3 fused matvecs ====================
__global__ void scatter_proj_k(const int* __restrict__ li_c, const int* __restrict__ ra_c,
                               const int* __restrict__ ra_dy,
                               int* __restrict__ li_grid, int* __restrict__ ra_grid,
                               uint8_t* __restrict__ rdy_grid, int* __restrict__ cursor,
                               int* __restrict__ lixy, int* __restrict__ raxy,
                               const float* __restrict__ li_f, const float* __restrict__ ra_f,
                               const float* __restrict__ ln_li_w, const float* __restrict__ ln_li_b,
                               const float* __restrict__ ln_ra_w, const float* __restrict__ ln_ra_b,
                               const float* __restrict__ a1iw, const float* __restrict__ a1ib,
                               const float* __restrict__ a2iw, const float* __restrict__ a2ib,
                               const float* __restrict__ q1w, const float* __restrict__ q1b,
                               const float* __restrict__ k1w, const float* __restrict__ k1b,
                               const float* __restrict__ v1w, const float* __restrict__ v1b,
                               const float* __restrict__ q2w, const float* __restrict__ q2b,
                               const float* __restrict__ k2w, const float* __restrict__ k2b,
                               const float* __restrict__ v2w, const float* __restrict__ v2b,
                               float* __restrict__ qp1, float* __restrict__ kp1, float* __restrict__ vp1,
                               float* __restrict__ qp2, float* __restrict__ kp2, float* __restrict__ vp2) {
    int bx = blockIdx.x, b = blockIdx.y, t = threadIdx.x;
    bool lidar = (bx < LB);
    int n = lidar ? NL : NR;
    int i = (lidar ? bx : bx - LB) * 256 + t;

    const float* feats = lidar ? li_f : ra_f;
    const float* lnw = lidar ? ln_li_w : ln_ra_w;
    const float* lnb = lidar ? ln_li_b : ln_ra_b;
    // lidar feeds q of branch1, k/v of branch2; radar feeds q of branch2, k/v of branch1
    const float* Asec[3] = { (lidar ? a1iw : a2iw) + 0 * C * C,
                             (lidar ? a2iw : a1iw) + 1 * C * C,
                             (lidar ? a2iw : a1iw) + 2 * C * C };
    const float* absec[3] = { (lidar ? a1ib : a2ib) + 0 * C,
                              (lidar ? a2ib : a1ib) + 1 * C,
                              (lidar ? a2ib : a1ib) + 2 * C };
    const float* Wsec[3] = { lidar ? q1w : q2w, lidar ? k2w : k1w, lidar ? v2w : v1w };
    const float* bsec[3] = { lidar ? q1b : q2b, lidar ? k2b : k1b, lidar ? v2b : v1b };
    float* outp[3] = { lidar ? qp1 : qp2, lidar ? kp2 : kp1, lidar ? vp2 : vp1 };

    __shared__ float sM[3][1024];
    __shared__ float sc[3][32];
    for (int p = t; p < 3072; p += 256) {
        int m = p >> 10, e = p & 1023, r = e >> 5, d = e & 31;
        float s = 0.f;
        #pragma unroll
        for (int c = 0; c < C; ++c) s += Asec[m][r * C + c] * Wsec[m][c * C + d];
        sM[m][e] = s;
    }
    if (t < 96) {
        int m = t >> 5, r = t & 31;
        float s = absec[m][r];
        #pragma unroll
        for (int c = 0; c < C; ++c) s += Asec[m][r * C + c] * bsec[m][c];
        sc[m][r] = s;
    }
    __syncthreads();
    if (i >= n) return;

    // slot assignment (spatially-ranked by 16x16 tile)
    int x = (lidar ? li_c : ra_c)[((size_t)b * n + i) * 2 + 0];
    int y = (lidar ? li_c : ra_c)[((size_t)b * n + i) * 2 + 1];
    int tile = ((x >> 4) << 5) | (y >> 4);
    int mod = lidar ? 0 : 1;
    int slot = atomicAdd(&cursor[(b * 2 + mod) * NTILE + tile], 1);
    size_t cellg = (size_t)b * HW + x * Ww + y;
    if (lidar) {
        li_grid[cellg] = slot;
        lixy[(size_t)b * NL + slot] = (x << 16) | y;
    } else {
        ra_grid[cellg] = slot;
        raxy[(size_t)b * NR + slot] = (x << 16) | y;
        if (ra_dy[(size_t)b * n + i] != 0) rdy_grid[cellg] = 0;
    }

    // LN
    float xv[C];
    const float4* f4 = (const float4*)(feats + ((size_t)b * n + i) * C);
    #pragma unroll
    for (int q = 0; q < 8; ++q) {
        float4 tv = f4[q];
        xv[4*q] = tv.x; xv[4*q+1] = tv.y; xv[4*q+2] = tv.z; xv[4*q+3] = tv.w;
    }
    float mu = 0.f;
    #pragma unroll
    for (int c = 0; c < C; ++c) mu += xv[c];
    mu *= (1.0f / C);
    float var = 0.f;
    #pragma unroll
    for (int c = 0; c < C; ++c) { float d = xv[c] - mu; var += d * d; }
    var *= (1.0f / C);
    float inv = 1.0f / sqrtf(var + EPS);
    #pragma unroll
    for (int c = 0; c < C; ++c) xv[c] = (xv[c] - mu) * inv * lnw[c] + lnb[c];

    // 3 matvecs -> maps at slot row
    #pragma unroll
    for (int m = 0; m < 3; ++m) {
        float4* o4 = (float4*)(outp[m] + ((size_t)b * n + slot) * C);
        #pragma unroll
        for (int rq = 0; rq < 8; ++rq) {
            float4 tv;
            float* tp = &tv.x;
            #pragma unroll
            for (int rr = 0; rr < 4; ++rr) {
                int r = rq * 4 + rr;
                float s = sc[m][r];
                #pragma unroll
                for (int d = 0; d < C; ++d) s += sM[m][r * C + d] * xv[d];
                tp[rr] = s;
            }
            o4[rq] = tv;
        }
    }
}

// ==================== 4) head-split slot-ordered attention (2 threads/query) ====================
__global__ void attn_slot_k(const int* __restrict__ li_grid, const int* __restrict__ ra_grid,
                            const uint8_t* __restrict__ rdy_grid,
                            const int* __restrict__ lixy, const int* __restrict__ raxy,
                            const float* __restrict__ qp1, const float* __restrict__ kp1,
                            const float* __restrict__ vp1, const float* __restrict__ qp2,
                            const float* __restrict__ kp2, const float* __restrict__ vp2,
                            const float* __restrict__ a1iw, const float* __restrict__ a1ib,
                            const float* __restrict__ a2iw, const float* __restrict__ a2ib,
                            const float* __restrict__ posw, const float* __restrict__ posb,
                            const float* __restrict__ a1ow, const float* __restrict__ a1ob,
                            const float* __restrict__ a2ow, const float* __restrict__ a2ob,
                            float* __restrict__ feat1, float* __restrict__ feat2) {
    int bx = blockIdx.x;
    bool br1 = (bx < LB2);
    int n = br1 ? NL : NR;
    int t = threadIdx.x;
    int qi = (br1 ? bx : bx - LB2) * 128 + (t >> 1);   // query index
    int h  = t & 1;                                     // head (0 or 1)
    int b = blockIdx.y;

    const float* Wo = br1 ? a1ow : a2ow;
    const float* bo = br1 ? a1ob : a2ob;
    const float* Aib = br1 ? a1ib : a2ib;
    const float* Av  = (br1 ? a1iw : a2iw) + 2 * C * C;
    __shared__ alignas(16) float sWo[1024];
    __shared__ alignas(16) float sbo[32], skinv[32], svinv[32];
    __shared__ alignas(16) float spe[288];
    for (int p = t; p < 1024; p += 256) sWo[p] = Wo[p];
    if (t < 32) {
        sbo[t] = bo[t];
        skinv[t] = Aib[32 + t];
        svinv[t] = Aib[64 + t];
    }
    for (int e = t; e < 288; e += 256) {      // projected pos-enc
        int j = e >> 5, r = e & 31;
        float sx = (float)DX9[j], sy = (float)DY9[j];
        float s = 0.f;
        #pragma unroll
        for (int c = 0; c < C; ++c) {
            float pe = posw[c * 2 + 0] * sx + posw[c * 2 + 1] * sy + posb[c];
            s += Av[r * C + c] * pe;
        }
        spe[e] = s;
    }
    __syncthreads();
    if (qi >= n) return;                       // pairs exit together

    int pc = (br1 ? lixy : raxy)[(size_t)b * n + qi];
    int x = pc >> 16, y = pc & 0xFFFF;
    float* featrow = (br1 ? feat1 : feat2) + ((size_t)b * n + qi) * C;

    if (br1) {
        // dy gate: 5x5 window, mod-513 wrap (coord 512 invalid) — uniform across the pair
        const uint8_t* rdy = rdy_grid + (size_t)b * HW;
        bool dy = false;
        #pragma unroll
        for (int dx = -2; dx <= 2 && !dy; ++dx) {
            int cx = x + dx;
            cx = (cx < 0) ? cx + 513 : (cx >= 513 ? cx - 513 : cx);
            if (cx == 512) continue;
            #pragma unroll
            for (int dyy = -2; dyy <= 2; ++dyy) {
                int cy = y + dyy;
                cy = (cy < 0) ? cy + 513 : (cy >= 513 ? cy - 513 : cy);
                if (cy == 512) continue;
                if (rdy[cx * Ww + cy] == 0) { dy = true; break; }
            }
        }
        if (!dy) {
            if (h == 0) {
                float4 z = {0.f, 0.f, 0.f, 0.f};
                float4* o4 = (float4*)featrow;
                #pragma unroll
                for (int q = 0; q < 8; ++q) o4[q] = z;
            }
            return;                            // pair exits together
        }
    }

    const int* kv_grid = (br1 ? ra_grid : li_grid) + (size_t)b * HW;
    int nkv = br1 ? NR : NL;
    const float* kmap = (br1 ? kp1 : kp2) + (size_t)b * nkv * C;
    const float* vmap = (br1 ? vp1 : vp2) + (size_t)b * nkv * C;

    int nidx[9];
    #pragma unroll
    for (int j = 0; j < 9; ++j) {
        int sx = x + DX9[j], sy = y + DY9[j];
        nidx[j] = (sx >= 0 && sx < Hh && sy >= 0 && sy < Ww) ? kv_grid[sx * Ww + sy] : -1;
    }

    // this thread's q half
    float qh[16];
    {
        const float4* q4 = (const float4*)((br1 ? qp1 : qp2) + ((size_t)b * n + qi) * C + h * 16);
        #pragma unroll
        for (int q = 0; q < 4; ++q) {
            float4 tv = q4[q];
            qh[4*q] = tv.x; qh[4*q+1] = tv.y; qh[4*q+2] = tv.z; qh[4*q+3] = tv.w;
        }
    }

    // scores for this head (invalid slots use bias-only K)
    float sc[9];
    #pragma unroll
    for (int j = 0; j < 9; ++j) {
        int idx = nidx[j];
        const float4* kp4 = (idx >= 0) ? (const float4*)(kmap + (size_t)idx * C + h * 16)
                                       : (const float4*)(skinv + h * 16);
        float s = 0.f;
        #pragma unroll
        for (int q = 0; q < 4; ++q) {
            float4 tv = kp4[q];
            s += qh[4*q] * tv.x + qh[4*q+1] * tv.y + qh[4*q+2] * tv.z + qh[4*q+3] * tv.w;
        }
        sc[j] = s * SCALE;
    }
    float m0 = sc[0];
    #pragma unroll
    for (int j = 1; j < 9; ++j) m0 = fmaxf(m0, sc[j]);
    float sum = 0.f;
    #pragma unroll
    for (int j = 0; j < 9; ++j) { sc[j] = expf(sc[j] - m0); sum += sc[j]; }
    float rs = 1.0f / sum;

    // PV for this head
    float o[16];
    #pragma unroll
    for (int d = 0; d < 16; ++d) o[d] = 0.f;
    #pragma unroll
    for (int j = 0; j < 9; ++j) {
        float a = sc[j] * rs;
        int idx = nidx[j];
        if (idx >= 0) {
            const float4* vp4 = (const float4*)(vmap + (size_t)idx * C + h * 16);
            #pragma unroll
            for (int q = 0; q < 4; ++q) {
                float4 tv = vp4[q];
                o[4*q]   += a * (tv.x + spe[j * 32 + h * 16 + 4*q]);
                o[4*q+1] += a * (tv.y + spe[j * 32 + h * 16 + 4*q+1]);
                o[4*q+2] += a * (tv.z + spe[j * 32 + h * 16 + 4*q+2]);
                o[4*q+3] += a * (tv.w + spe[j * 32 + h * 16 + 4*q+3]);
            }
        } else {
            #pragma unroll
            for (int d = 0; d < 16; ++d) o[d] += a * svinv[h * 16 + d];
        }
    }

    // partial out-proj: P[r] = Wo[r, h*16 : h*16+16] . o
    float P[32];
    #pragma unroll
    for (int r = 0; r < C; ++r) {
        float s = 0.f;
        #pragma unroll
        for (int c = 0; c < 16; ++c) s += sWo[r * C + h * 16 + c] * o[c];
        P[r] = s;
    }
    // combine across the head pair (lanes t and t^1 are in the same wave)
    #pragma unroll
    for (int r = 0; r < C; ++r) P[r] += __shfl_xor(P[r], 1);
    if (h == 0) {
        float4* o4 = (float4*)featrow;
        #pragma unroll
        for (int rq = 0; rq < 8; ++rq) {
            float4 tv;
            tv.x = P[4*rq]   + sbo[4*rq];
            tv.y = P[4*rq+1] + sbo[4*rq+1];
            tv.z = P[4*rq+2] + sbo[4*rq+2];
            tv.w = P[4*rq+3] + sbo[4*rq+3];
            o4[rq] = tv;
        }
    }
}

// ==================== 5) densify: thread per cell, coalesced canvas writes ====================
__global__ void canvas_k(const int* __restrict__ li_grid, const int* __restrict__ ra_grid,
                         const float* __restrict__ feat1, const float* __restrict__ feat2,
                         float* __restrict__ out_li, float* __restrict__ out_ra) {
    int b = blockIdx.y;
    int cell = blockIdx.x * 256 + threadIdx.x;
    size_t gidx = (size_t)b * HW + cell;
    size_t obase = (size_t)b * C * HW + cell;

    int li = li_grid[gidx];
    float v[C];
    if (li >= 0) {
        const float4* f = (const float4*)(feat1 + ((size_t)b * NL + li) * C);
        #pragma unroll
        for (int q = 0; q < 8; ++q) {
            float4 t = f[q];
            v[4*q] = t.x; v[4*q+1] = t.y; v[4*q+2] = t.z; v[4*q+3] = t.w;
        }
    } else {
        #pragma unroll
        for (int c = 0; c < C; ++c) v[c] = 0.f;
    }
    #pragma unroll
    for (int c = 0; c < C; ++c) out_li[obase + (size_t)c * HW] = v[c];

    int ra = ra_grid[gidx];
    if (ra >= 0) {
        const float4* f = (const float4*)(feat2 + ((size_t)b * NR + ra) * C);
        #pragma unroll
        for (int q = 0; q < 8; ++q) {
            float4 t = f[q];
            v[4*q] = t.x; v[4*q+1] = t.y; v[4*q+2] = t.z; v[4*q+3] = t.w;
        }
    } else {
        #pragma unroll
        for (int c = 0; c < C; ++c) v[c] = 0.f;
    }
    #pragma unroll
    for (int c = 0; c < C; ++c) out_ra[obase + (size_t)c * HW] = v[c];
}

extern "C" void kernel_launch(void* const* d_in, const int* in_sizes, int n_in,
                              void* d_out, int out_size, void* d_ws, size_t ws_size,
                              hipStream_t stream) {
    const float*   li_f  = (const float*)d_in[0];
    const int*     li_c  = (const int*)d_in[1];
    const float*   ra_f  = (const float*)d_in[2];
    const int*     ra_c  = (const int*)d_in[3];
    const int*     ra_dy = (const int*)d_in[4];   // jnp bool staged as int32
    const float* ln_li_w = (const float*)d_in[5];
    const float* ln_li_b = (const float*)d_in[6];
    const float* ln_ra_w = (const float*)d_in[7];
    const float* ln_ra_b = (const float*)d_in[8];
    const float* q1w = (const float*)d_in[9],  *q1b = (const float*)d_in[10];
    const float* k1w = (const float*)d_in[11], *k1b = (const float*)d_in[12];
    const float* v1w = (const float*)d_in[13], *v1b = (const float*)d_in[14];
    const float* q2w = (const float*)d_in[15], *q2b = (const float*)d_in[16];
    const float* k2w = (const float*)d_in[17], *k2b = (const float*)d_in[18];
    const float* v2w = (const float*)d_in[19], *v2b = (const float*)d_in[20];
    const float* posw = (const float*)d_in[21], *posb = (const float*)d_in[22];
    const float* a1iw = (const float*)d_in[23], *a1ib = (const float*)d_in[24];
    const float* a1ow = (const float*)d_in[25], *a1ob = (const float*)d_in[26];
    const float* a2iw = (const float*)d_in[27], *a2ib = (const float*)d_in[28];
    const float* a2ow = (const float*)d_in[29], *a2ob = (const float*)d_in[30];

    // ---- workspace carve-up (256B aligned); grids+rdy contiguous for one memset ----
    char* ws = (char*)d_ws;
    size_t off = 0;
    auto carve = [&](size_t bytes) { void* p = ws + off; off += (bytes + 255) & ~(size_t)255; return p; };
    int*     li_grid  = (int*)carve((size_t)B * HW * 4);
    int*     ra_grid  = (int*)carve((size_t)B * HW * 4);
    uint8_t* rdy_grid = (uint8_t*)carve((size_t)B * HW);
    size_t   init_bytes = off;                             // -> 0xFF
    int*     cnt      = (int*)carve((size_t)4 * NTILE * 4);
    int*     cursor   = (int*)carve((size_t)4 * NTILE * 4);
    int*     lixy     = (int*)carve((size_t)B * NL * 4);
    int*     raxy     = (int*)carve((size_t)B * NR * 4);
    float*   qp1 = (float*)carve((size_t)B * NL * C * 4);
    float*   kp1 = (float*)carve((size_t)B * NR * C * 4);
    float*   vp1 = (float*)carve((size_t)B * NR * C * 4);
    float*   qp2 = (float*)carve((size_t)B * NR * C * 4);
    float*   kp2 = (float*)carve((size_t)B * NL * C * 4);
    float*   vp2 = (float*)carve((size_t)B * NL * C * 4);
    float*   feat1 = (float*)carve((size_t)B * NL * C * 4);
    float*   feat2 = (float*)carve((size_t)B * NR * C * 4);
    (void)ws_size; (void)n_in; (void)in_sizes; (void)out_size;

    float* out_li = (float*)d_out;
    float* out_ra = out_li + (size_t)B * C * HW;

    // 1) grids -1 / rdy 0xFF ; 2) cnt = 0
    hipMemsetAsync(li_grid, 0xFF, init_bytes, stream);
    hipMemsetAsync(cnt, 0, (size_t)4 * NTILE * 4, stream);

    // 3) tile histogram
    count_k<<<dim3(GBL, B), dim3(256), 0, stream>>>(li_c, ra_c, cnt);
    // 4) exclusive scan -> cursor
    scan_k<<<dim3(4), dim3(NTILE), 0, stream>>>(cnt, cursor);
    // 5) slot scatter + LN + projections (maps in spatially-ranked slot order)
    scatter_proj_k<<<dim3(LB + RB, B), dim3(256), 0, stream>>>(
        li_c, ra_c, ra_dy, li_grid, ra_grid, rdy_grid, cursor, lixy, raxy,
        li_f, ra_f, ln_li_w, ln_li_b, ln_ra_w, ln_ra_b,
        a1iw, a1ib, a2iw, a2ib,
        q1w, q1b, k1w, k1b, v1w, v1b, q2w, q2b, k2w, k2b, v2w, v2b,
        qp1, kp1, vp1, qp2, kp2, vp2);
    // 6) head-split slot-ordered attention (2 threads/query)
    attn_slot_k<<<dim3(LB2 + RB2, B), dim3(256), 0, stream>>>(
        li_grid, ra_grid, rdy_grid, lixy, raxy,
        qp1, kp1, vp1, qp2, kp2, vp2,
        a1iw, a1ib, a2iw, a2ib, posw, posb, a1ow, a1ob, a2ow, a2ob,
        feat1, feat2);
    // 7) densify (coalesced writes)
    canvas_k<<<dim3(HW / 256, B), dim3(256), 0, stream>>>(
        li_grid, ra_grid, feat1, feat2, out_li, out_ra);
}